// Round 8
// baseline (719.589 us; speedup 1.0000x reference)
//
#include <hip/hip_runtime.h>

#define B_ 128   // batch

typedef __attribute__((ext_vector_type(4))) float f4;
typedef __attribute__((ext_vector_type(2))) float f2;

// ---------------- split-K MLP layer ----------------
// P[zz][b][j] = sum_{k in slice zz} act[b,k] * W[k,j]
// act[b,k] = (NSUM==0) ? A[b,k] : relu(bias_in[k] + sum_s A[s][b][k])
// grid = (NCH, 16, NZZ), block = 256. Each block: 8 batch rows x 256 cols x KS k-slice.
template<int NSUM, int NCH, int NZZ, int KS, int N_T, int KTOT>
__global__ __launch_bounds__(256) void mlp4(
    const float* __restrict__ A, const float* __restrict__ bias_in,
    const float* __restrict__ W, float* __restrict__ P) {
  constexpr int BG = 8;
  __shared__ float sA[KS][10];   // pad 8->10: conflict-free writes, 8B-aligned f2 reads

  // XCD affinity: zz % 8 == flat % 8 so all 16 y-blocks sharing a W-slice
  // land on one XCD (W slice stays in that XCD's L2).
  const int flat = blockIdx.x + NCH * (blockIdx.y + 16 * blockIdx.z);
  const int idx  = flat >> 3;
  const int nch  = idx % NCH;
  const int t2   = idx / NCH;
  const int yy   = t2 & 15;
  const int zhi  = t2 >> 4;
  const int zz   = (flat & 7) + 8 * zhi;

  const int tid = threadIdx.x;
  const int b0  = yy * BG;
  const int k0  = zz * KS;
  const int klen = (NSUM == 0) ? min(KTOT - k0, KS) : KS;

  if (NSUM == 0) {
    for (int g = 0; g < BG; ++g)
      for (int k = tid; k < klen; k += 256)
        sA[k][g] = A[(size_t)(b0 + g) * KTOT + k0 + k];   // coalesced
  } else {
    constexpr int K4 = KS / 4;
    for (int i2 = tid; i2 < BG * K4; i2 += 256) {
      int g = i2 & 7, k4 = i2 >> 3;
      f4 v = *(const f4*)(bias_in + k0 + 4 * k4);
      for (int s = 0; s < NSUM; ++s)
        v += *(const f4*)(A + ((size_t)s * B_ + b0 + g) * KTOT + k0 + 4 * k4);
      v.x = fmaxf(v.x, 0.f); v.y = fmaxf(v.y, 0.f);
      v.z = fmaxf(v.z, 0.f); v.w = fmaxf(v.w, 0.f);
      sA[4 * k4 + 0][g] = v.x; sA[4 * k4 + 1][g] = v.y;
      sA[4 * k4 + 2][g] = v.z; sA[4 * k4 + 3][g] = v.w;
    }
  }
  __syncthreads();

  const int cg_ = tid & 63;   // 64 f4 col-groups = 256 cols
  const int rg  = tid >> 6;   // 4 row-groups x 2 rows = 8 rows
  f4 acc0 = (f4)0.f, acc1 = (f4)0.f;
  const float* wp = W + (size_t)k0 * N_T + nch * 256 + 4 * cg_;
#pragma unroll 8
  for (int k = 0; k < klen; ++k) {
    f4 w = *(const f4*)wp; wp += N_T;
    f2 a = *(const f2*)&sA[k][rg * 2];   // wave-uniform broadcast ds_read_b64
    acc0 += a.x * w;
    acc1 += a.y * w;
  }
  float* pp = P + ((size_t)zz * B_ + b0 + rg * 2) * N_T + nch * 256 + 4 * cg_;
  *(f4*)pp = acc0;
  *(f4*)(pp + N_T) = acc1;
}

// ---------------- layer 5 (N=264, K=512, NSUM=16, SPLITK=4) + counter init ----------------
// grid = (1, 16, 4), block = 256
__global__ __launch_bounds__(256) void mlp_l5(
    const float* __restrict__ Pprev, const float* __restrict__ bias_in,
    const float* __restrict__ W5, float* __restrict__ P5,
    unsigned int* __restrict__ maxEnc, unsigned int* __restrict__ cnt) {
  __shared__ float sA[8][128];
  const int tid = threadIdx.x;
  const int b0 = blockIdx.y * 8;
  const int k0 = blockIdx.z * 128;

  // init atomics scratch for ccc_fin (this kernel strictly precedes it in-stream)
  if (blockIdx.z == 0 && tid < 8) {
    maxEnc[b0 + tid] = 0u;      // 0 encodes "below all reals" under the monotone map
    cnt[b0 + tid] = 0u;
  }

  {
    int g = tid >> 5, k4 = tid & 31;
    f4 v = *(const f4*)(bias_in + k0 + 4 * k4);
    for (int s = 0; s < 16; ++s)
      v += *(const f4*)(Pprev + ((size_t)s * B_ + b0 + g) * 512 + k0 + 4 * k4);
    v.x = fmaxf(v.x, 0.f); v.y = fmaxf(v.y, 0.f);
    v.z = fmaxf(v.z, 0.f); v.w = fmaxf(v.w, 0.f);
    *(f4*)&sA[g][4 * k4] = v;
  }
  __syncthreads();

  if (tid < 132) {
    f2 acc[8];
#pragma unroll
    for (int r = 0; r < 8; ++r) acc[r] = (f2)0.f;
    const float* wp = W5 + (size_t)k0 * 264 + 2 * tid;
#pragma unroll 4
    for (int k = 0; k < 128; ++k) {
      f2 w = *(const f2*)wp;
      wp += 264;
#pragma unroll
      for (int r = 0; r < 8; ++r) acc[r] += sA[r][k] * w;
    }
#pragma unroll
    for (int r = 0; r < 8; ++r)
      *(f2*)(P5 + ((size_t)blockIdx.z * B_ + b0 + r) * 264 + 2 * tid) = acc[r];
  }
}

// monotone float<->uint encoding (unsigned compare == float compare)
__device__ __forceinline__ unsigned int encf(float f) {
  unsigned int u = __float_as_uint(f);
  return (u & 0x80000000u) ? ~u : (u | 0x80000000u);
}
__device__ __forceinline__ float decf(unsigned int e) {
  return __uint_as_float((e & 0x80000000u) ? (e ^ 0x80000000u) : ~e);
}

// ---------------- ccc + fused finalize ----------------
// grid = B*C = 8192 blocks, block = 256. Last-arriving block per b writes output.
__global__ __launch_bounds__(256) void ccc_fin(
    const float* __restrict__ Tr, const float* __restrict__ Ti,
    const float* __restrict__ P5, const float* __restrict__ b5,
    unsigned int* __restrict__ maxEnc, unsigned int* __restrict__ cnt,
    float* __restrict__ out) {
  const int bc = blockIdx.x;
  const int b  = bc >> 6;
  const int tid = threadIdx.x;

  __shared__ __align__(16) float sx[104];
  __shared__ __align__(16) float sy[104];
  __shared__ float sred[4];
  __shared__ unsigned int s_last;

  if (tid < 100) {
    float tr = b5[tid], ti = b5[100 + tid];
#pragma unroll
    for (int s = 0; s < 4; ++s) {
      tr += P5[(size_t)s * B_ * 264 + b * 264 + tid];
      ti += P5[(size_t)s * B_ * 264 + b * 264 + 100 + tid];
    }
    float inv = rsqrtf(fmaf(tr, tr, ti * ti));
    sx[tid] = tr * inv;
    sy[tid] = ti * inv;
  }
  __syncthreads();

  const f4* Tr4 = reinterpret_cast<const f4*>(Tr + (size_t)bc * 10000);
  const f4* Ti4 = reinterpret_cast<const f4*>(Ti + (size_t)bc * 10000);

  float a0 = 0.f, a1 = 0.f, a2 = 0.f, a3 = 0.f;
#pragma unroll 2
  for (int i = tid; i < 2500; i += 256) {
    f4 t = __builtin_nontemporal_load(Tr4 + i);
    f4 u = __builtin_nontemporal_load(Ti4 + i);
    int n  = i / 25;
    int m0 = (i - n * 25) * 4;
    float xn = sx[n], yn = sy[n];
    float4 xm = *reinterpret_cast<const float4*>(&sx[m0]);
    float4 ym = *reinterpret_cast<const float4*>(&sy[m0]);
    a0 = fmaf(t.x, fmaf(xn, xm.x, yn * ym.x), a0);
    a1 = fmaf(u.x, fmaf(yn, xm.x, -(xn * ym.x)), a1);
    a2 = fmaf(t.y, fmaf(xn, xm.y, yn * ym.y), a2);
    a3 = fmaf(u.y, fmaf(yn, xm.y, -(xn * ym.y)), a3);
    a0 = fmaf(t.z, fmaf(xn, xm.z, yn * ym.z), a0);
    a1 = fmaf(u.z, fmaf(yn, xm.z, -(xn * ym.z)), a1);
    a2 = fmaf(t.w, fmaf(xn, xm.w, yn * ym.w), a2);
    a3 = fmaf(u.w, fmaf(yn, xm.w, -(xn * ym.w)), a3);
  }
  float acc = (a0 + a1) + (a2 + a3);

  for (int off = 32; off; off >>= 1) acc += __shfl_down(acc, off);
  if ((tid & 63) == 0) sred[tid >> 6] = acc;
  __syncthreads();

  if (tid == 0) {
    float c = (sred[0] + sred[1]) + (sred[2] + sred[3]);
    atomicMax(&maxEnc[b], encf(c));       // device-scope, commutative -> deterministic
    __threadfence();                      // release: max visible before arrival
    unsigned int old = atomicAdd(&cnt[b], 1u);
    s_last = (old == 63u);
  }
  __syncthreads();

  if (s_last) {
    __threadfence();                      // acquire: see all 64 maxes
    float m = decf(atomicOr(&maxEnc[b], 0u));
    float scale = sqrtf(1e-15f / m);
    if (tid < 100) {
      out[b * 264 + tid]       = sx[tid] * scale;
      out[b * 264 + 100 + tid] = sy[tid] * scale;
    } else if (tid < 164) {
      int j = tid + 100;                  // 200..263 passthrough
      float v = b5[j];
#pragma unroll
      for (int s = 0; s < 4; ++s)
        v += P5[(size_t)s * B_ * 264 + b * 264 + j];
      out[b * 264 + j] = v;
    }
  }
}

extern "C" void kernel_launch(void* const* d_in, const int* in_sizes, int n_in,
                              void* d_out, int out_size, void* d_ws, size_t ws_size,
                              hipStream_t stream) {
  const float* sample1 = (const float*)d_in[0];
  const float* Tr = (const float*)d_in[2];
  const float* Ti = (const float*)d_in[3];
  const float* W1 = (const float*)d_in[4];  const float* b1 = (const float*)d_in[5];
  const float* W2 = (const float*)d_in[6];  const float* b2 = (const float*)d_in[7];
  const float* W3 = (const float*)d_in[8];  const float* b3 = (const float*)d_in[9];
  const float* W4 = (const float*)d_in[10]; const float* b4 = (const float*)d_in[11];
  const float* W5 = (const float*)d_in[12]; const float* b5 = (const float*)d_in[13];

  float* ws = (float*)d_ws;
  float* Pa = ws;                           // 16*128*1024 floats (8 MB)
  float* Pb = Pa + 16 * B_ * 1024;          // 16*128*1024 floats (8 MB)
  float* P5 = Pb + 16 * B_ * 1024;          // 4*128*264
  unsigned int* maxEnc = (unsigned int*)(P5 + 4 * B_ * 264);   // 128
  unsigned int* cnt    = maxEnc + 128;                          // 128

  float* out = (float*)d_out;

  // L1: A[128,303] @ W1[303,1024], SPLITK=8 (KS=40) -> Pa[8]
  mlp4<0, 4, 8, 40, 1024, 303><<<dim3(4, 16, 8), 256, 0, stream>>>(sample1, nullptr, W1, Pa);
  // L2: relu(Pa+b1) @ W2[1024,1024], SPLITK=16 -> Pb[16]
  mlp4<8, 4, 16, 64, 1024, 1024><<<dim3(4, 16, 16), 256, 0, stream>>>(Pa, b1, W2, Pb);
  // L3: relu(Pb+b2) @ W3[1024,1024], SPLITK=16 -> Pa[16]
  mlp4<16, 4, 16, 64, 1024, 1024><<<dim3(4, 16, 16), 256, 0, stream>>>(Pb, b2, W3, Pa);
  // L4: relu(Pa+b3) @ W4[1024,512], SPLITK=16 -> Pb[16]
  mlp4<16, 2, 16, 64, 512, 1024><<<dim3(2, 16, 16), 256, 0, stream>>>(Pa, b3, W4, Pb);
  // L5: relu(Pb+b4) @ W5[512,264], SPLITK=4 -> P5[4]; also zero atomics scratch
  mlp_l5<<<dim3(1, 16, 4), 256, 0, stream>>>(Pb, b4, W5, P5, maxEnc, cnt);
  // ccc + finalize fused
  ccc_fin<<<dim3(B_ * 64), 256, 0, stream>>>(Tr, Ti, P5, b5, maxEnc, cnt, out);
}

// Round 9
// 167.949 us; speedup vs baseline: 4.2846x; 4.2846x over previous
//
#include <hip/hip_runtime.h>

#define B_ 128   // batch

typedef __attribute__((ext_vector_type(4))) float f4;
typedef __attribute__((ext_vector_type(2))) float f2;

// ---------------- split-K MLP layer ----------------
// P[zz][b][j] = sum_{k in slice zz} act[b,k] * W[k,j]
// act[b,k] = (NSUM==0) ? A[b,k] : relu(bias_in[k] + sum_s A[s][b][k])
// grid = (NCH, 16, NZZ), block = 256. Each block: 8 batch rows x 256 cols x KS k-slice.
template<int NSUM, int NCH, int NZZ, int KS, int N_T, int KTOT>
__global__ __launch_bounds__(256) void mlp4(
    const float* __restrict__ A, const float* __restrict__ bias_in,
    const float* __restrict__ W, float* __restrict__ P) {
  constexpr int BG = 8;
  __shared__ float sA[KS][10];   // pad 8->10: conflict-free writes, 8B-aligned f2 reads

  // XCD affinity: zz % 8 == flat % 8 so all 16 y-blocks sharing a W-slice
  // land on one XCD (W slice stays in that XCD's L2).
  const int flat = blockIdx.x + NCH * (blockIdx.y + 16 * blockIdx.z);
  const int idx  = flat >> 3;
  const int nch  = idx % NCH;
  const int t2   = idx / NCH;
  const int yy   = t2 & 15;
  const int zhi  = t2 >> 4;
  const int zz   = (flat & 7) + 8 * zhi;

  const int tid = threadIdx.x;
  const int b0  = yy * BG;
  const int k0  = zz * KS;
  const int klen = (NSUM == 0) ? min(KTOT - k0, KS) : KS;

  if (NSUM == 0) {
    for (int g = 0; g < BG; ++g)
      for (int k = tid; k < klen; k += 256)
        sA[k][g] = A[(size_t)(b0 + g) * KTOT + k0 + k];   // coalesced
  } else {
    constexpr int K4 = KS / 4;
    for (int i2 = tid; i2 < BG * K4; i2 += 256) {
      int g = i2 & 7, k4 = i2 >> 3;
      f4 v = *(const f4*)(bias_in + k0 + 4 * k4);
      for (int s = 0; s < NSUM; ++s)
        v += *(const f4*)(A + ((size_t)s * B_ + b0 + g) * KTOT + k0 + 4 * k4);
      v.x = fmaxf(v.x, 0.f); v.y = fmaxf(v.y, 0.f);
      v.z = fmaxf(v.z, 0.f); v.w = fmaxf(v.w, 0.f);
      sA[4 * k4 + 0][g] = v.x; sA[4 * k4 + 1][g] = v.y;
      sA[4 * k4 + 2][g] = v.z; sA[4 * k4 + 3][g] = v.w;
    }
  }
  __syncthreads();

  const int cg_ = tid & 63;   // 64 f4 col-groups = 256 cols
  const int rg  = tid >> 6;   // 4 row-groups x 2 rows = 8 rows
  f4 acc0 = (f4)0.f, acc1 = (f4)0.f;
  const float* wp = W + (size_t)k0 * N_T + nch * 256 + 4 * cg_;
#pragma unroll 8
  for (int k = 0; k < klen; ++k) {
    f4 w = *(const f4*)wp; wp += N_T;
    f2 a = *(const f2*)&sA[k][rg * 2];   // wave-uniform broadcast ds_read_b64
    acc0 += a.x * w;
    acc1 += a.y * w;
  }
  float* pp = P + ((size_t)zz * B_ + b0 + rg * 2) * N_T + nch * 256 + 4 * cg_;
  *(f4*)pp = acc0;
  *(f4*)(pp + N_T) = acc1;
}

// ---------------- layer 5 (N=264, K=512, NSUM=16, SPLITK=4) ----------------
// grid = (1, 16, 4), block = 256
__global__ __launch_bounds__(256) void mlp_l5(
    const float* __restrict__ Pprev, const float* __restrict__ bias_in,
    const float* __restrict__ W5, float* __restrict__ P5) {
  __shared__ float sA[8][128];
  const int tid = threadIdx.x;
  const int b0 = blockIdx.y * 8;
  const int k0 = blockIdx.z * 128;
  {
    int g = tid >> 5, k4 = tid & 31;
    f4 v = *(const f4*)(bias_in + k0 + 4 * k4);
    for (int s = 0; s < 16; ++s)
      v += *(const f4*)(Pprev + ((size_t)s * B_ + b0 + g) * 512 + k0 + 4 * k4);
    v.x = fmaxf(v.x, 0.f); v.y = fmaxf(v.y, 0.f);
    v.z = fmaxf(v.z, 0.f); v.w = fmaxf(v.w, 0.f);
    *(f4*)&sA[g][4 * k4] = v;
  }
  __syncthreads();

  if (tid < 132) {
    f2 acc[8];
#pragma unroll
    for (int r = 0; r < 8; ++r) acc[r] = (f2)0.f;
    const float* wp = W5 + (size_t)k0 * 264 + 2 * tid;
#pragma unroll 4
    for (int k = 0; k < 128; ++k) {
      f2 w = *(const f2*)wp;
      wp += 264;
#pragma unroll
      for (int r = 0; r < 8; ++r) acc[r] += sA[r][k] * w;
    }
#pragma unroll
    for (int r = 0; r < 8; ++r)
      *(f2*)(P5 + ((size_t)blockIdx.z * B_ + b0 + r) * 264 + 2 * tid) = acc[r];
  }
}

// ---------------- ccc[b,c] = Re( conj(theta)^T T theta )  (raw) ----------------
// grid = B*C = 8192 blocks, block = 256. NO atomics/fences: keep the streaming
// loop fence-free so the compiler pipelines loads (R8 post-mortem: a device-
// scope fence in the tail de-pipelined this loop -> 7x slowdown).
__global__ __launch_bounds__(256) void ccc_kernel(
    const float* __restrict__ Tr, const float* __restrict__ Ti,
    const float* __restrict__ P5, const float* __restrict__ b5,
    float* __restrict__ ccc) {
  const int bc = blockIdx.x;
  const int b  = bc >> 6;
  const int tid = threadIdx.x;

  __shared__ __align__(16) float sx[104];
  __shared__ __align__(16) float sy[104];
  if (tid < 100) {
    float tr = b5[tid], ti = b5[100 + tid];
#pragma unroll
    for (int s = 0; s < 4; ++s) {
      tr += P5[(size_t)s * B_ * 264 + b * 264 + tid];
      ti += P5[(size_t)s * B_ * 264 + b * 264 + 100 + tid];
    }
    float inv = rsqrtf(fmaf(tr, tr, ti * ti));
    sx[tid] = tr * inv;
    sy[tid] = ti * inv;
  }
  __syncthreads();

  const f4* Tr4 = reinterpret_cast<const f4*>(Tr + (size_t)bc * 10000);
  const f4* Ti4 = reinterpret_cast<const f4*>(Ti + (size_t)bc * 10000);

  float a0 = 0.f, a1 = 0.f, a2 = 0.f, a3 = 0.f;
#pragma unroll 2
  for (int i = tid; i < 2500; i += 256) {
    f4 t = __builtin_nontemporal_load(Tr4 + i);
    f4 u = __builtin_nontemporal_load(Ti4 + i);
    int n  = i / 25;
    int m0 = (i - n * 25) * 4;
    float xn = sx[n], yn = sy[n];
    float4 xm = *reinterpret_cast<const float4*>(&sx[m0]);
    float4 ym = *reinterpret_cast<const float4*>(&sy[m0]);
    a0 = fmaf(t.x, fmaf(xn, xm.x, yn * ym.x), a0);
    a1 = fmaf(u.x, fmaf(yn, xm.x, -(xn * ym.x)), a1);
    a2 = fmaf(t.y, fmaf(xn, xm.y, yn * ym.y), a2);
    a3 = fmaf(u.y, fmaf(yn, xm.y, -(xn * ym.y)), a3);
    a0 = fmaf(t.z, fmaf(xn, xm.z, yn * ym.z), a0);
    a1 = fmaf(u.z, fmaf(yn, xm.z, -(xn * ym.z)), a1);
    a2 = fmaf(t.w, fmaf(xn, xm.w, yn * ym.w), a2);
    a3 = fmaf(u.w, fmaf(yn, xm.w, -(xn * ym.w)), a3);
  }
  float acc = (a0 + a1) + (a2 + a3);

  for (int off = 32; off; off >>= 1) acc += __shfl_down(acc, off);
  __shared__ float sred[4];
  if ((tid & 63) == 0) sred[tid >> 6] = acc;
  __syncthreads();
  if (tid == 0) ccc[bc] = (sred[0] + sred[1]) + (sred[2] + sred[3]);
}

// ---------------- finalize ----------------
// grid = 128 blocks (one per b), block = 256
__global__ __launch_bounds__(256) void finalize_kernel(
    const float* __restrict__ P5, const float* __restrict__ b5,
    const float* __restrict__ ccc, float* __restrict__ out) {
  const int b = blockIdx.x;
  const int tid = threadIdx.x;
  __shared__ float s_t1[264];
  __shared__ float s_scale;

  for (int j = tid; j < 264; j += 256) {
    float v = b5[j];
#pragma unroll
    for (int s = 0; s < 4; ++s)
      v += P5[(size_t)s * B_ * 264 + b * 264 + j];
    s_t1[j] = v;
  }
  if (tid < 64) {
    float v = ccc[b * 64 + tid];
    for (int off = 32; off; off >>= 1) v = fmaxf(v, __shfl_down(v, off));
    if (tid == 0) s_scale = sqrtf(1e-15f / v);
  }
  __syncthreads();

  const float scale = s_scale;
  for (int j = tid; j < 264; j += 256) {
    float o;
    if (j < 200) {
      int n = (j < 100) ? j : (j - 100);
      float tr = s_t1[n];
      float ti = s_t1[100 + n];
      float inv = rsqrtf(fmaf(tr, tr, ti * ti));
      o = ((j < 100) ? tr : ti) * inv * scale;
    } else {
      o = s_t1[j];
    }
    out[b * 264 + j] = o;
  }
}

extern "C" void kernel_launch(void* const* d_in, const int* in_sizes, int n_in,
                              void* d_out, int out_size, void* d_ws, size_t ws_size,
                              hipStream_t stream) {
  const float* sample1 = (const float*)d_in[0];
  const float* Tr = (const float*)d_in[2];
  const float* Ti = (const float*)d_in[3];
  const float* W1 = (const float*)d_in[4];  const float* b1 = (const float*)d_in[5];
  const float* W2 = (const float*)d_in[6];  const float* b2 = (const float*)d_in[7];
  const float* W3 = (const float*)d_in[8];  const float* b3 = (const float*)d_in[9];
  const float* W4 = (const float*)d_in[10]; const float* b4 = (const float*)d_in[11];
  const float* W5 = (const float*)d_in[12]; const float* b5 = (const float*)d_in[13];

  float* ws = (float*)d_ws;
  float* Pa = ws;                           // 16*128*1024 floats (8 MB)
  float* Pb = Pa + 16 * B_ * 1024;          // 16*128*1024 floats (8 MB)
  float* P5 = Pb + 16 * B_ * 1024;          // 4*128*264
  float* cc = P5 + 4 * B_ * 264;            // 8192

  float* out = (float*)d_out;

  // L1: A[128,303] @ W1[303,1024], SPLITK=8 (KS=40) -> Pa[8]
  mlp4<0, 4, 8, 40, 1024, 303><<<dim3(4, 16, 8), 256, 0, stream>>>(sample1, nullptr, W1, Pa);
  // L2: relu(Pa+b1) @ W2[1024,1024], SPLITK=16 -> Pb[16]
  mlp4<8, 4, 16, 64, 1024, 1024><<<dim3(4, 16, 16), 256, 0, stream>>>(Pa, b1, W2, Pb);
  // L3: relu(Pb+b2) @ W3[1024,1024], SPLITK=16 -> Pa[16]
  mlp4<16, 4, 16, 64, 1024, 1024><<<dim3(4, 16, 16), 256, 0, stream>>>(Pb, b2, W3, Pa);
  // L4: relu(Pa+b3) @ W4[1024,512], SPLITK=16 -> Pb[16]
  mlp4<16, 2, 16, 64, 512, 1024><<<dim3(2, 16, 16), 256, 0, stream>>>(Pa, b3, W4, Pb);
  // L5: relu(Pb+b4) @ W5[512,264], SPLITK=4 -> P5[4]
  mlp_l5<<<dim3(1, 16, 4), 256, 0, stream>>>(Pb, b4, W5, P5);
  // ccc then finalize (separate kernels; fence-free streaming)
  ccc_kernel<<<dim3(B_ * 64), 256, 0, stream>>>(Tr, Ti, P5, b5, cc);
  finalize_kernel<<<dim3(B_), 256, 0, stream>>>(P5, b5, cc, out);
}

// Round 10
// 164.217 us; speedup vs baseline: 4.3819x; 1.0227x over previous
//
#include <hip/hip_runtime.h>

#define B_ 128   // batch

typedef __attribute__((ext_vector_type(4))) float f4;
typedef __attribute__((ext_vector_type(2))) float f2;

// ---------------- split-K MLP layer ----------------
// P[zz][b][j] = sum_{k in slice zz} act[b,k] * W[k,j]
// act[b,k] = (NSUM==0) ? A[b,k] : relu(bias_in[k] + sum_s A[s][b][k])
// grid = (NCH, 16, NZZ), block = 256. Each block: 8 batch rows x 256 cols x KS k-slice.
template<int NSUM, int NCH, int NZZ, int KS, int N_T, int KTOT>
__global__ __launch_bounds__(256) void mlp4(
    const float* __restrict__ A, const float* __restrict__ bias_in,
    const float* __restrict__ W, float* __restrict__ P) {
  constexpr int BG = 8;
  __shared__ float sA[KS][10];   // pad 8->10: conflict-free writes, 8B-aligned f2 reads

  // XCD affinity: zz % 8 == flat % 8 so all 16 y-blocks sharing a W-slice
  // land on one XCD (W slice stays in that XCD's L2).
  const int flat = blockIdx.x + NCH * (blockIdx.y + 16 * blockIdx.z);
  const int idx  = flat >> 3;
  const int nch  = idx % NCH;
  const int t2   = idx / NCH;
  const int yy   = t2 & 15;
  const int zhi  = t2 >> 4;
  const int zz   = (flat & 7) + 8 * zhi;

  const int tid = threadIdx.x;
  const int b0  = yy * BG;
  const int k0  = zz * KS;
  const int klen = (NSUM == 0) ? min(KTOT - k0, KS) : KS;

  if (NSUM == 0) {
    for (int g = 0; g < BG; ++g)
      for (int k = tid; k < klen; k += 256)
        sA[k][g] = A[(size_t)(b0 + g) * KTOT + k0 + k];   // coalesced
  } else {
    constexpr int K4 = KS / 4;
    for (int i2 = tid; i2 < BG * K4; i2 += 256) {
      int g = i2 & 7, k4 = i2 >> 3;
      f4 v = *(const f4*)(bias_in + k0 + 4 * k4);
      for (int s = 0; s < NSUM; ++s)
        v += *(const f4*)(A + ((size_t)s * B_ + b0 + g) * KTOT + k0 + 4 * k4);
      v.x = fmaxf(v.x, 0.f); v.y = fmaxf(v.y, 0.f);
      v.z = fmaxf(v.z, 0.f); v.w = fmaxf(v.w, 0.f);
      sA[4 * k4 + 0][g] = v.x; sA[4 * k4 + 1][g] = v.y;
      sA[4 * k4 + 2][g] = v.z; sA[4 * k4 + 3][g] = v.w;
    }
  }
  __syncthreads();

  const int cg_ = tid & 63;   // 64 f4 col-groups = 256 cols
  const int rg  = tid >> 6;   // 4 row-groups x 2 rows = 8 rows
  f4 acc0 = (f4)0.f, acc1 = (f4)0.f;
  const float* wp = W + (size_t)k0 * N_T + nch * 256 + 4 * cg_;
#pragma unroll 8
  for (int k = 0; k < klen; ++k) {
    f4 w = *(const f4*)wp; wp += N_T;
    f2 a = *(const f2*)&sA[k][rg * 2];   // wave-uniform broadcast ds_read_b64
    acc0 += a.x * w;
    acc1 += a.y * w;
  }
  float* pp = P + ((size_t)zz * B_ + b0 + rg * 2) * N_T + nch * 256 + 4 * cg_;
  *(f4*)pp = acc0;
  *(f4*)(pp + N_T) = acc1;
}

// ---------------- layer 5 (N=264, K=512, NSUM=16, SPLITK=4) ----------------
// grid = (1, 16, 4), block = 256
__global__ __launch_bounds__(256) void mlp_l5(
    const float* __restrict__ Pprev, const float* __restrict__ bias_in,
    const float* __restrict__ W5, float* __restrict__ P5) {
  __shared__ float sA[8][128];
  const int tid = threadIdx.x;
  const int b0 = blockIdx.y * 8;
  const int k0 = blockIdx.z * 128;
  {
    int g = tid >> 5, k4 = tid & 31;
    f4 v = *(const f4*)(bias_in + k0 + 4 * k4);
    for (int s = 0; s < 16; ++s)
      v += *(const f4*)(Pprev + ((size_t)s * B_ + b0 + g) * 512 + k0 + 4 * k4);
    v.x = fmaxf(v.x, 0.f); v.y = fmaxf(v.y, 0.f);
    v.z = fmaxf(v.z, 0.f); v.w = fmaxf(v.w, 0.f);
    *(f4*)&sA[g][4 * k4] = v;
  }
  __syncthreads();

  if (tid < 132) {
    f2 acc[8];
#pragma unroll
    for (int r = 0; r < 8; ++r) acc[r] = (f2)0.f;
    const float* wp = W5 + (size_t)k0 * 264 + 2 * tid;
#pragma unroll 4
    for (int k = 0; k < 128; ++k) {
      f2 w = *(const f2*)wp;
      wp += 264;
#pragma unroll
      for (int r = 0; r < 8; ++r) acc[r] += sA[r][k] * w;
    }
#pragma unroll
    for (int r = 0; r < 8; ++r)
      *(f2*)(P5 + ((size_t)blockIdx.z * B_ + b0 + r) * 264 + 2 * tid) = acc[r];
  }
}

// ---------------- ccc[b,c] = Re( conj(theta)^T T theta )  (raw) ----------------
// grid = B*C = 8192 blocks, block = 256.
// ALL 20 global loads issued up front (register-staged, static indices) so each
// wave keeps ~320B/lane in flight; FMA runs against drained loads afterwards.
// Tail (2500 = 9*256 + 196) is branchless: zero t/u + zero sx/sy[100..103]
// -> fmaf no-ops, bit-identical accumulation order vs R5/R9.
__global__ __launch_bounds__(256) void ccc_kernel(
    const float* __restrict__ Tr, const float* __restrict__ Ti,
    const float* __restrict__ P5, const float* __restrict__ b5,
    float* __restrict__ ccc) {
  const int bc = blockIdx.x;
  const int b  = bc >> 6;
  const int tid = threadIdx.x;

  __shared__ __align__(16) float sx[104];
  __shared__ __align__(16) float sy[104];
  if (tid < 104) {
    if (tid < 100) {
      float tr = b5[tid], ti = b5[100 + tid];
#pragma unroll
      for (int s = 0; s < 4; ++s) {
        tr += P5[(size_t)s * B_ * 264 + b * 264 + tid];
        ti += P5[(size_t)s * B_ * 264 + b * 264 + 100 + tid];
      }
      float inv = rsqrtf(fmaf(tr, tr, ti * ti));
      sx[tid] = tr * inv;
      sy[tid] = ti * inv;
    } else {
      sx[tid] = 0.f;   // guard rows for branchless tail (n up to 102)
      sy[tid] = 0.f;
    }
  }
  __syncthreads();

  const f4* Tr4 = reinterpret_cast<const f4*>(Tr + (size_t)bc * 10000);
  const f4* Ti4 = reinterpret_cast<const f4*>(Ti + (size_t)bc * 10000);

  // Issue ALL loads up front.
  f4 t[10], u[10];
  const bool tail = tid < (2500 - 9 * 256);   // 196
#pragma unroll
  for (int j = 0; j < 9; ++j) {
    t[j] = __builtin_nontemporal_load(Tr4 + tid + 256 * j);
    u[j] = __builtin_nontemporal_load(Ti4 + tid + 256 * j);
  }
  if (tail) {
    t[9] = __builtin_nontemporal_load(Tr4 + tid + 2304);
    u[9] = __builtin_nontemporal_load(Ti4 + tid + 2304);
  } else {
    t[9] = (f4)0.f;
    u[9] = (f4)0.f;
  }

  float a0 = 0.f, a1 = 0.f, a2 = 0.f, a3 = 0.f;
#pragma unroll
  for (int j = 0; j < 10; ++j) {
    const int i = tid + 256 * j;
    int n  = i / 25;
    int m0 = (i - n * 25) * 4;
    float xn = sx[n], yn = sy[n];
    float4 xm = *reinterpret_cast<const float4*>(&sx[m0]);
    float4 ym = *reinterpret_cast<const float4*>(&sy[m0]);
    a0 = fmaf(t[j].x, fmaf(xn, xm.x, yn * ym.x), a0);
    a1 = fmaf(u[j].x, fmaf(yn, xm.x, -(xn * ym.x)), a1);
    a2 = fmaf(t[j].y, fmaf(xn, xm.y, yn * ym.y), a2);
    a3 = fmaf(u[j].y, fmaf(yn, xm.y, -(xn * ym.y)), a3);
    a0 = fmaf(t[j].z, fmaf(xn, xm.z, yn * ym.z), a0);
    a1 = fmaf(u[j].z, fmaf(yn, xm.z, -(xn * ym.z)), a1);
    a2 = fmaf(t[j].w, fmaf(xn, xm.w, yn * ym.w), a2);
    a3 = fmaf(u[j].w, fmaf(yn, xm.w, -(xn * ym.w)), a3);
  }
  float acc = (a0 + a1) + (a2 + a3);

  for (int off = 32; off; off >>= 1) acc += __shfl_down(acc, off);
  __shared__ float sred[4];
  if ((tid & 63) == 0) sred[tid >> 6] = acc;
  __syncthreads();
  if (tid == 0) ccc[bc] = (sred[0] + sred[1]) + (sred[2] + sred[3]);
}

// ---------------- finalize ----------------
// grid = 128 blocks (one per b), block = 256
__global__ __launch_bounds__(256) void finalize_kernel(
    const float* __restrict__ P5, const float* __restrict__ b5,
    const float* __restrict__ ccc, float* __restrict__ out) {
  const int b = blockIdx.x;
  const int tid = threadIdx.x;
  __shared__ float s_t1[264];
  __shared__ float s_scale;

  for (int j = tid; j < 264; j += 256) {
    float v = b5[j];
#pragma unroll
    for (int s = 0; s < 4; ++s)
      v += P5[(size_t)s * B_ * 264 + b * 264 + j];
    s_t1[j] = v;
  }
  if (tid < 64) {
    float v = ccc[b * 64 + tid];
    for (int off = 32; off; off >>= 1) v = fmaxf(v, __shfl_down(v, off));
    if (tid == 0) s_scale = sqrtf(1e-15f / v);
  }
  __syncthreads();

  const float scale = s_scale;
  for (int j = tid; j < 264; j += 256) {
    float o;
    if (j < 200) {
      int n = (j < 100) ? j : (j - 100);
      float tr = s_t1[n];
      float ti = s_t1[100 + n];
      float inv = rsqrtf(fmaf(tr, tr, ti * ti));
      o = ((j < 100) ? tr : ti) * inv * scale;
    } else {
      o = s_t1[j];
    }
    out[b * 264 + j] = o;
  }
}

extern "C" void kernel_launch(void* const* d_in, const int* in_sizes, int n_in,
                              void* d_out, int out_size, void* d_ws, size_t ws_size,
                              hipStream_t stream) {
  const float* sample1 = (const float*)d_in[0];
  const float* Tr = (const float*)d_in[2];
  const float* Ti = (const float*)d_in[3];
  const float* W1 = (const float*)d_in[4];  const float* b1 = (const float*)d_in[5];
  const float* W2 = (const float*)d_in[6];  const float* b2 = (const float*)d_in[7];
  const float* W3 = (const float*)d_in[8];  const float* b3 = (const float*)d_in[9];
  const float* W4 = (const float*)d_in[10]; const float* b4 = (const float*)d_in[11];
  const float* W5 = (const float*)d_in[12]; const float* b5 = (const float*)d_in[13];

  float* ws = (float*)d_ws;
  float* Pa = ws;                           // 16*128*1024 floats (8 MB)
  float* Pb = Pa + 16 * B_ * 1024;          // 16*128*1024 floats (8 MB)
  float* P5 = Pb + 16 * B_ * 1024;          // 4*128*264
  float* cc = P5 + 4 * B_ * 264;            // 8192

  float* out = (float*)d_out;

  // L1: A[128,303] @ W1[303,1024], SPLITK=8 (KS=40) -> Pa[8]
  mlp4<0, 4, 8, 40, 1024, 303><<<dim3(4, 16, 8), 256, 0, stream>>>(sample1, nullptr, W1, Pa);
  // L2: relu(Pa+b1) @ W2[1024,1024], SPLITK=16 -> Pb[16]
  mlp4<8, 4, 16, 64, 1024, 1024><<<dim3(4, 16, 16), 256, 0, stream>>>(Pa, b1, W2, Pb);
  // L3: relu(Pb+b2) @ W3[1024,1024], SPLITK=16 -> Pa[16]
  mlp4<16, 4, 16, 64, 1024, 1024><<<dim3(4, 16, 16), 256, 0, stream>>>(Pb, b2, W3, Pa);
  // L4: relu(Pa+b3) @ W4[1024,512], SPLITK=16 -> Pb[16]
  mlp4<16, 2, 16, 64, 512, 1024><<<dim3(2, 16, 16), 256, 0, stream>>>(Pa, b3, W4, Pb);
  // L5: relu(Pb+b4) @ W5[512,264], SPLITK=4 -> P5[4]
  mlp_l5<<<dim3(1, 16, 4), 256, 0, stream>>>(Pb, b4, W5, P5);
  // ccc then finalize (separate kernels; fence-free streaming)
  ccc_kernel<<<dim3(B_ * 64), 256, 0, stream>>>(Tr, Ti, P5, b5, cc);
  finalize_kernel<<<dim3(B_), 256, 0, stream>>>(P5, b5, cc, out);
}

// Round 11
// 163.286 us; speedup vs baseline: 4.4069x; 1.0057x over previous
//
#include <hip/hip_runtime.h>

#define B_ 128   // batch

typedef __attribute__((ext_vector_type(4))) float f4;
typedef __attribute__((ext_vector_type(2))) float f2;

// ---------------- split-K MLP layer ----------------
// P[zz][b][j] = sum_{k in slice zz} act[b,k] * W[k,j]
// act[b,k] = (NSUM==0) ? A[b,k] : relu(bias_in[k] + sum_s A[s][b][k])
// grid = (NCH, 16, NZZ), block = 256. Each block: 8 batch rows x 256 cols x KS k-slice.
template<int NSUM, int NCH, int NZZ, int KS, int N_T, int KTOT>
__global__ __launch_bounds__(256) void mlp4(
    const float* __restrict__ A, const float* __restrict__ bias_in,
    const float* __restrict__ W, float* __restrict__ P) {
  constexpr int BG = 8;
  __shared__ float sA[KS][10];   // pad 8->10: conflict-free writes, 8B-aligned f2 reads

  // XCD affinity: zz % 8 == flat % 8 so all 16 y-blocks sharing a W-slice
  // land on one XCD (W slice stays in that XCD's L2).
  const int flat = blockIdx.x + NCH * (blockIdx.y + 16 * blockIdx.z);
  const int idx  = flat >> 3;
  const int nch  = idx % NCH;
  const int t2   = idx / NCH;
  const int yy   = t2 & 15;
  const int zhi  = t2 >> 4;
  const int zz   = (flat & 7) + 8 * zhi;

  const int tid = threadIdx.x;
  const int b0  = yy * BG;
  const int k0  = zz * KS;
  const int klen = (NSUM == 0) ? min(KTOT - k0, KS) : KS;

  if (NSUM == 0) {
    for (int g = 0; g < BG; ++g)
      for (int k = tid; k < klen; k += 256)
        sA[k][g] = A[(size_t)(b0 + g) * KTOT + k0 + k];   // coalesced
  } else {
    constexpr int K4 = KS / 4;
    for (int i2 = tid; i2 < BG * K4; i2 += 256) {
      int g = i2 & 7, k4 = i2 >> 3;
      f4 v = *(const f4*)(bias_in + k0 + 4 * k4);
      for (int s = 0; s < NSUM; ++s)
        v += *(const f4*)(A + ((size_t)s * B_ + b0 + g) * KTOT + k0 + 4 * k4);
      v.x = fmaxf(v.x, 0.f); v.y = fmaxf(v.y, 0.f);
      v.z = fmaxf(v.z, 0.f); v.w = fmaxf(v.w, 0.f);
      sA[4 * k4 + 0][g] = v.x; sA[4 * k4 + 1][g] = v.y;
      sA[4 * k4 + 2][g] = v.z; sA[4 * k4 + 3][g] = v.w;
    }
  }
  __syncthreads();

  const int cg_ = tid & 63;   // 64 f4 col-groups = 256 cols
  const int rg  = tid >> 6;   // 4 row-groups x 2 rows = 8 rows
  f4 acc0 = (f4)0.f, acc1 = (f4)0.f;
  const float* wp = W + (size_t)k0 * N_T + nch * 256 + 4 * cg_;
#pragma unroll 8
  for (int k = 0; k < klen; ++k) {
    f4 w = *(const f4*)wp; wp += N_T;
    f2 a = *(const f2*)&sA[k][rg * 2];   // wave-uniform broadcast ds_read_b64
    acc0 += a.x * w;
    acc1 += a.y * w;
  }
  float* pp = P + ((size_t)zz * B_ + b0 + rg * 2) * N_T + nch * 256 + 4 * cg_;
  *(f4*)pp = acc0;
  *(f4*)(pp + N_T) = acc1;
}

// ---------------- layer 5 (N=264, K=512, NSUM=16, SPLITK=4) ----------------
// grid = (1, 16, 4), block = 256
__global__ __launch_bounds__(256) void mlp_l5(
    const float* __restrict__ Pprev, const float* __restrict__ bias_in,
    const float* __restrict__ W5, float* __restrict__ P5) {
  __shared__ float sA[8][128];
  const int tid = threadIdx.x;
  const int b0 = blockIdx.y * 8;
  const int k0 = blockIdx.z * 128;
  {
    int g = tid >> 5, k4 = tid & 31;
    f4 v = *(const f4*)(bias_in + k0 + 4 * k4);
    for (int s = 0; s < 16; ++s)
      v += *(const f4*)(Pprev + ((size_t)s * B_ + b0 + g) * 512 + k0 + 4 * k4);
    v.x = fmaxf(v.x, 0.f); v.y = fmaxf(v.y, 0.f);
    v.z = fmaxf(v.z, 0.f); v.w = fmaxf(v.w, 0.f);
    *(f4*)&sA[g][4 * k4] = v;
  }
  __syncthreads();

  if (tid < 132) {
    f2 acc[8];
#pragma unroll
    for (int r = 0; r < 8; ++r) acc[r] = (f2)0.f;
    const float* wp = W5 + (size_t)k0 * 264 + 2 * tid;
#pragma unroll 4
    for (int k = 0; k < 128; ++k) {
      f2 w = *(const f2*)wp;
      wp += 264;
#pragma unroll
      for (int r = 0; r < 8; ++r) acc[r] += sA[r][k] * w;
    }
#pragma unroll
    for (int r = 0; r < 8; ++r)
      *(f2*)(P5 + ((size_t)blockIdx.z * B_ + b0 + r) * 264 + 2 * tid) = acc[r];
  }
}

// ---------------- ccc via precomputed X/Y in LDS ----------------
// grid = 1024 blocks (b * 8 + cgroup), block = 1024 threads.
// Per block: build X[i] = xn*xm + yn*ym, Y[i] = yn*xm - xn*ym (i = n*25+m0/4
// packed as f4 over m) ONCE, then stream 8 c's of T against conflict-free,
// lane-consecutive LDS reads:  acc += t*X[i] + u*Y[i].
// Per-wave partials go to ccp[bc][16] (no barriers in the c-loop -> loads
// pipeline across c's); finalize sums them deterministically.
__global__ __launch_bounds__(1024) void ccc_kernel(
    const float* __restrict__ Tr, const float* __restrict__ Ti,
    const float* __restrict__ P5, const float* __restrict__ b5,
    float* __restrict__ ccp) {
  __shared__ __align__(16) float Xs[10000];   // 2500 f4
  __shared__ __align__(16) float Ys[10000];   // 2500 f4
  __shared__ __align__(16) float sx[104];
  __shared__ __align__(16) float sy[104];

  const int tid = threadIdx.x;
  const int b   = blockIdx.x >> 3;
  const int bc0 = b * 64 + (blockIdx.x & 7) * 8;

  // theta (unit modulus)
  if (tid < 100) {
    float tr = b5[tid], ti = b5[100 + tid];
#pragma unroll
    for (int s = 0; s < 4; ++s) {
      tr += P5[(size_t)s * B_ * 264 + b * 264 + tid];
      ti += P5[(size_t)s * B_ * 264 + b * 264 + 100 + tid];
    }
    float inv = rsqrtf(fmaf(tr, tr, ti * ti));
    sx[tid] = tr * inv;
    sy[tid] = ti * inv;
  }

  const f4* Tr4 = reinterpret_cast<const f4*>(Tr) + (size_t)bc0 * 2500;
  const f4* Ti4 = reinterpret_cast<const f4*>(Ti) + (size_t)bc0 * 2500;
  const bool tail = tid < (2500 - 2 * 1024);   // 452

  // prefetch c=0 into buffer 0 BEFORE the barrier (independent of LDS)
  f4 tb[2][3], ub[2][3];
  tb[0][0] = __builtin_nontemporal_load(Tr4 + tid);
  tb[0][1] = __builtin_nontemporal_load(Tr4 + tid + 1024);
  tb[0][2] = tail ? __builtin_nontemporal_load(Tr4 + tid + 2048) : (f4)0.f;
  ub[0][0] = __builtin_nontemporal_load(Ti4 + tid);
  ub[0][1] = __builtin_nontemporal_load(Ti4 + tid + 1024);
  ub[0][2] = tail ? __builtin_nontemporal_load(Ti4 + tid + 2048) : (f4)0.f;
  __syncthreads();

  // build X/Y (gathers happen ONCE, amortized over 8 c's)
  f4* X4 = reinterpret_cast<f4*>(Xs);
  f4* Y4 = reinterpret_cast<f4*>(Ys);
  for (int i = tid; i < 2500; i += 1024) {
    int n  = i / 25;
    int m0 = (i - n * 25) * 4;
    float xn = sx[n], yn = sy[n];
    float4 xm = *reinterpret_cast<const float4*>(&sx[m0]);
    float4 ym = *reinterpret_cast<const float4*>(&sy[m0]);
    f4 xv, yv;
    xv.x = fmaf(xn, xm.x, yn * ym.x);  yv.x = fmaf(yn, xm.x, -(xn * ym.x));
    xv.y = fmaf(xn, xm.y, yn * ym.y);  yv.y = fmaf(yn, xm.y, -(xn * ym.y));
    xv.z = fmaf(xn, xm.z, yn * ym.z);  yv.z = fmaf(yn, xm.z, -(xn * ym.z));
    xv.w = fmaf(xn, xm.w, yn * ym.w);  yv.w = fmaf(yn, xm.w, -(xn * ym.w));
    X4[i] = xv;
    Y4[i] = yv;
  }
  __syncthreads();

  const int i2 = tail ? (tid + 2048) : 2499;   // clamped: t/u are 0 there, X/Y finite

#pragma unroll
  for (int q = 0; q < 8; ++q) {
    const int cur = q & 1;
    const int nxt = cur ^ 1;
    if (q < 7) {   // prefetch next c
      const f4* tp = Tr4 + (size_t)(q + 1) * 2500;
      const f4* up = Ti4 + (size_t)(q + 1) * 2500;
      tb[nxt][0] = __builtin_nontemporal_load(tp + tid);
      tb[nxt][1] = __builtin_nontemporal_load(tp + tid + 1024);
      tb[nxt][2] = tail ? __builtin_nontemporal_load(tp + tid + 2048) : (f4)0.f;
      ub[nxt][0] = __builtin_nontemporal_load(up + tid);
      ub[nxt][1] = __builtin_nontemporal_load(up + tid + 1024);
      ub[nxt][2] = tail ? __builtin_nontemporal_load(up + tid + 2048) : (f4)0.f;
    }

    float a0 = 0.f, a1 = 0.f, a2 = 0.f, a3 = 0.f;
    {
      f4 X = X4[tid], Y = Y4[tid];
      f4 t = tb[cur][0], u = ub[cur][0];
      a0 = fmaf(t.x, X.x, a0); a1 = fmaf(u.x, Y.x, a1);
      a2 = fmaf(t.y, X.y, a2); a3 = fmaf(u.y, Y.y, a3);
      a0 = fmaf(t.z, X.z, a0); a1 = fmaf(u.z, Y.z, a1);
      a2 = fmaf(t.w, X.w, a2); a3 = fmaf(u.w, Y.w, a3);
    }
    {
      f4 X = X4[tid + 1024], Y = Y4[tid + 1024];
      f4 t = tb[cur][1], u = ub[cur][1];
      a0 = fmaf(t.x, X.x, a0); a1 = fmaf(u.x, Y.x, a1);
      a2 = fmaf(t.y, X.y, a2); a3 = fmaf(u.y, Y.y, a3);
      a0 = fmaf(t.z, X.z, a0); a1 = fmaf(u.z, Y.z, a1);
      a2 = fmaf(t.w, X.w, a2); a3 = fmaf(u.w, Y.w, a3);
    }
    {
      f4 X = X4[i2], Y = Y4[i2];
      f4 t = tb[cur][2], u = ub[cur][2];
      a0 = fmaf(t.x, X.x, a0); a1 = fmaf(u.x, Y.x, a1);
      a2 = fmaf(t.y, X.y, a2); a3 = fmaf(u.y, Y.y, a3);
      a0 = fmaf(t.z, X.z, a0); a1 = fmaf(u.z, Y.z, a1);
      a2 = fmaf(t.w, X.w, a2); a3 = fmaf(u.w, Y.w, a3);
    }
    float acc = (a0 + a1) + (a2 + a3);
    for (int off = 32; off; off >>= 1) acc += __shfl_down(acc, off);
    if ((tid & 63) == 0)
      ccp[(size_t)(bc0 + q) * 16 + (tid >> 6)] = acc;   // per-wave partial
  }
}

// ---------------- finalize ----------------
// grid = 128 blocks (one per b), block = 256
__global__ __launch_bounds__(256) void finalize_kernel(
    const float* __restrict__ P5, const float* __restrict__ b5,
    const float* __restrict__ ccp, float* __restrict__ out) {
  const int b = blockIdx.x;
  const int tid = threadIdx.x;
  __shared__ float s_t1[264];
  __shared__ float s_scale;

  for (int j = tid; j < 264; j += 256) {
    float v = b5[j];
#pragma unroll
    for (int s = 0; s < 4; ++s)
      v += P5[(size_t)s * B_ * 264 + b * 264 + j];
    s_t1[j] = v;
  }
  if (tid < 64) {
    const float* pp = ccp + ((size_t)(b * 64 + tid)) * 16;
    float v = 0.f;
#pragma unroll
    for (int w = 0; w < 16; ++w) v += pp[w];           // deterministic order
    for (int off = 32; off; off >>= 1) v = fmaxf(v, __shfl_down(v, off));
    if (tid == 0) s_scale = sqrtf(1e-15f / v);
  }
  __syncthreads();

  const float scale = s_scale;
  for (int j = tid; j < 264; j += 256) {
    float o;
    if (j < 200) {
      int n = (j < 100) ? j : (j - 100);
      float tr = s_t1[n];
      float ti = s_t1[100 + n];
      float inv = rsqrtf(fmaf(tr, tr, ti * ti));
      o = ((j < 100) ? tr : ti) * inv * scale;
    } else {
      o = s_t1[j];
    }
    out[b * 264 + j] = o;
  }
}

extern "C" void kernel_launch(void* const* d_in, const int* in_sizes, int n_in,
                              void* d_out, int out_size, void* d_ws, size_t ws_size,
                              hipStream_t stream) {
  const float* sample1 = (const float*)d_in[0];
  const float* Tr = (const float*)d_in[2];
  const float* Ti = (const float*)d_in[3];
  const float* W1 = (const float*)d_in[4];  const float* b1 = (const float*)d_in[5];
  const float* W2 = (const float*)d_in[6];  const float* b2 = (const float*)d_in[7];
  const float* W3 = (const float*)d_in[8];  const float* b3 = (const float*)d_in[9];
  const float* W4 = (const float*)d_in[10]; const float* b4 = (const float*)d_in[11];
  const float* W5 = (const float*)d_in[12]; const float* b5 = (const float*)d_in[13];

  float* ws = (float*)d_ws;
  float* Pa = ws;                           // 16*128*1024 floats (8 MB)
  float* Pb = Pa + 16 * B_ * 1024;          // 16*128*1024 floats (8 MB)
  float* P5 = Pb + 16 * B_ * 1024;          // 4*128*264
  float* ccp = P5 + 4 * B_ * 264;           // 8192*16 per-wave partials

  float* out = (float*)d_out;

  // L1: A[128,303] @ W1[303,1024], SPLITK=8 (KS=40) -> Pa[8]
  mlp4<0, 4, 8, 40, 1024, 303><<<dim3(4, 16, 8), 256, 0, stream>>>(sample1, nullptr, W1, Pa);
  // L2: relu(Pa+b1) @ W2[1024,1024], SPLITK=16 -> Pb[16]
  mlp4<8, 4, 16, 64, 1024, 1024><<<dim3(4, 16, 16), 256, 0, stream>>>(Pa, b1, W2, Pb);
  // L3: relu(Pb+b2) @ W3[1024,1024], SPLITK=16 -> Pa[16]
  mlp4<16, 4, 16, 64, 1024, 1024><<<dim3(4, 16, 16), 256, 0, stream>>>(Pb, b2, W3, Pa);
  // L4: relu(Pa+b3) @ W4[1024,512], SPLITK=16 -> Pb[16]
  mlp4<16, 2, 16, 64, 512, 1024><<<dim3(2, 16, 16), 256, 0, stream>>>(Pa, b3, W4, Pb);
  // L5: relu(Pb+b4) @ W5[512,264], SPLITK=4 -> P5[4]
  mlp_l5<<<dim3(1, 16, 4), 256, 0, stream>>>(Pb, b4, W5, P5);
  // ccc (X/Y-in-LDS, c-group of 8) then finalize
  ccc_kernel<<<dim3(1024), 1024, 0, stream>>>(Tr, Ti, P5, b5, ccp);
  finalize_kernel<<<dim3(B_), 256, 0, stream>>>(P5, b5, ccp, out);
}